// Round 6
// baseline (52.462 us; speedup 1.0000x reference)
//
#include <hip/hip_runtime.h>

// ---------------------------------------------------------------------------
// SNN Perceptron Equalizer (LIF recurrent net), MI355X
//
//  * ff = xt@W_in^T collapses to table rows. P[t][seg][sym][h] (fp64-built,
//    fp32-stored). P2[t][s0][s1][h] = fp32(Pseg0[s0]) + fp32(Pseg1[s1])
//    (bit-identical to adding the two rows at runtime) -> ONE load per step,
//    plus the seg2 row on the 8/32 steps that span 3 embedding rows (HAS3).
//  * One WAVE per batch element; lane l holds h=4l..4l+3 (f32x4). Spike
//    masks via __ballot (SGPRs); ids peeled with SALU. No LDS in the scan.
//  * ff loads issued TWO steps ahead (3-slot rotation, symbol-only addrs);
//    WT rows for z_{t-1} issued one step ahead, EXACTLY c rows (no dummy
//    traffic). sched_barrier(0) pins the pipeline each step.
//  * z_sum[b,:] = 32*b_out + sum_h cnt[b,h]*W_out[:,h]; rate = spikes/2^25.
// ---------------------------------------------------------------------------

typedef float f32x4 __attribute__((ext_vector_type(4)));

#define T_STEPS 32
#define FDIM    41
#define ODIM    16
#define BDIM    4096
#define MF      164

#define P_FLOATS   (32 * 3 * 16 * 256)
#define WT_ROWS    257
#define WT_FLOATS  (WT_ROWS * 256)
#define P2_FLOATS  (32 * 16 * 16 * 256)
// byte offsets in d_ws
#define WT_OFF     (P_FLOATS * 4)
#define CNT_OFF    ((P_FLOATS + WT_FLOATS) * 4)
#define P2_OFF     (CNT_OFF + 16)
#define WS_NEED    (P2_OFF + P2_FLOATS * 4)

// does timestep T span 3 embedding rows?  ((164T)&127) > 92
#define HAS3(T) ((((T) * MF) & 127) > 92)

// ---------------------------------------------------------------------------
// K1: build P table (fp64 accum; 4-symbol groups), transpose W_rec,
//     zero spike counter.
// ---------------------------------------------------------------------------
__global__ __launch_bounds__(256) void k_prep(const float* __restrict__ emb,
                                              const float* __restrict__ W_in,
                                              const float* __restrict__ W_rec,
                                              float* __restrict__ P,
                                              float* __restrict__ WT,
                                              int* __restrict__ counter)
{
    const int bid = blockIdx.x;
    const int tid = threadIdx.x;

    if (bid < 384) {
        const int g  = bid & 3;          // symbol group: symbols 4g..4g+3
        const int ts = bid >> 2;
        const int t  = ts / 3;
        const int si = ts % 3;
        const int k0   = t * MF;
        const int f    = (k0 >> 7) + si;
        const int base = f << 7;
        const int c0   = max(k0, base) - base;
        const int c1   = min(k0 + MF, base + 128) - base;
        const int len  = c1 - c0;

        if (len <= 0) {
            #pragma unroll
            for (int s = 0; s < 4; ++s)
                P[((t * 3 + si) * 16 + 4 * g + s) * 256 + tid] = 0.0f;
            return;
        }

        __shared__ float emb_lds[4][128];
        for (int idx = tid; idx < 4 * 128; idx += 256) {
            const int s = idx >> 7, u = idx & 127;
            if (u < len) emb_lds[s][u] = emb[((4 * g + s) << 7) + c0 + u];
        }
        __syncthreads();

        const int j0 = base + c0 - k0;   // window-local start column
        double a0 = 0.0, a1 = 0.0, a2 = 0.0, a3 = 0.0;
        for (int u = 0; u < len; ++u) {
            const double w = (double)W_in[tid * MF + j0 + u];
            a0 += w * (double)emb_lds[0][u];
            a1 += w * (double)emb_lds[1][u];
            a2 += w * (double)emb_lds[2][u];
            a3 += w * (double)emb_lds[3][u];
        }
        P[((t * 3 + si) * 16 + 4 * g + 0) * 256 + tid] = (float)a0;
        P[((t * 3 + si) * 16 + 4 * g + 1) * 256 + tid] = (float)a1;
        P[((t * 3 + si) * 16 + 4 * g + 2) * 256 + tid] = (float)a2;
        P[((t * 3 + si) * 16 + 4 * g + 3) * 256 + tid] = (float)a3;
    } else {
        const int h = bid - 384;                // 0..256
        if (h < 256) {
            WT[h * 256 + tid] = W_rec[tid * 256 + h];
        } else {
            WT[256 * 256 + tid] = 0.0f;
            if (tid == 0) *counter = 0;
        }
    }
}

// ---------------------------------------------------------------------------
// K1b: P2[t][s0][s1][h] = P[t][0][s0][h] + P[t][1][s1][h]  (fp32, same
// rounding as the runtime add it replaces). grid = 32*16 blocks.
// ---------------------------------------------------------------------------
__global__ __launch_bounds__(256) void k_comb(const float* __restrict__ P,
                                              float* __restrict__ P2)
{
    const int t  = blockIdx.x >> 4;
    const int s0 = blockIdx.x & 15;
    const int h  = threadIdx.x;
    const float a = P[((t * 3 + 0) * 16 + s0) * 256 + h];
    const float* __restrict__ pb = P + ((t * 3 + 1) * 16) * 256 + h;
    float* __restrict__ dst = P2 + ((t * 16 + s0) * 16) * 256 + h;
    #pragma unroll
    for (int s1 = 0; s1 < 16; ++s1)
        dst[s1 * 256] = a + pb[s1 * 256];
}

// ---------------------------------------------------------------------------
// K2: main LIF scan. grid = BDIM/4 blocks, 4 independent waves/block.
// ---------------------------------------------------------------------------
template <bool USEP2>
__global__ __launch_bounds__(256) void k_main(const int* __restrict__ x,
                                              const float* __restrict__ P,
                                              const float* __restrict__ P2,
                                              const float* __restrict__ WT,
                                              const float* __restrict__ W_out,
                                              const float* __restrict__ b_out,
                                              float* __restrict__ out,
                                              int* __restrict__ counter)
{
#pragma clang fp contract(off)
    __shared__ float cnt_lds[4][256];
    __shared__ int   red[4];

    const int tid  = threadIdx.x;
    const int lane = tid & 63;
    const int wv   = __builtin_amdgcn_readfirstlane(tid >> 6);
    const int b    = blockIdx.x * 4 + wv;

    const f32x4* __restrict__ P4   = (const f32x4*)P;
    const f32x4* __restrict__ P2_4 = (const f32x4*)P2;
    const f32x4* __restrict__ WT4  = (const f32x4*)WT;

    // symbols: one coalesced load, then readlane -> SGPRs
    const int xv = (lane < FDIM) ? x[b * FDIM + lane] : 0;
    int sym[FDIM];
    #pragma unroll
    for (int f = 0; f < FDIM; ++f)
        sym[f] = __builtin_amdgcn_readlane(xv, f);

    const f32x4 zero4 = {0.f, 0.f, 0.f, 0.f};
    f32x4 vm = zero4, cur = zero4;
    int n0 = 0, n1 = 0, n2 = 0, n3 = 0;

    // ff slots (3-deep rotation; 'b' halves only used when !USEP2)
    f32x4 p0a = zero4, p0b = zero4, p1a = zero4, p1b = zero4,
          p2a = zero4, p2b = zero4;
    f32x4 qA = zero4, qB = zero4;                 // seg3 rows (1 ahead)
    f32x4 wA0 = zero4, wA1 = zero4, wA2 = zero4, wA3 = zero4;
    f32x4 wB0 = zero4, wB1 = zero4, wB2 = zero4, wB3 = zero4;
    f32x4 rextA = zero4, rextB = zero4;
    int cntA = 0, cntB = 0;

    // prologue: ff rows for t=0 -> slot p0, t=1 -> slot p1
    if constexpr (USEP2) {
        p0a = P2_4[((0 * 16 + sym[0]) * 16 + sym[1]) * 64 + lane];
        p1a = P2_4[((1 * 16 + sym[1]) * 16 + sym[2]) * 64 + lane];
    } else {
        p0a = P4[(0 * 16 + sym[0]) * 64 + lane];
        p0b = P4[(1 * 16 + sym[1]) * 64 + lane];
        p1a = P4[((3 + 0) * 16 + sym[1]) * 64 + lane];
        p1b = P4[((3 + 1) * 16 + sym[2]) * 64 + lane];
    }

    #define PEEL(dst)                                                         \
        do {                                                                  \
            if (m0)      { dst = 4 * __builtin_ctzll(m0) + 0; m0 &= m0 - 1; } \
            else if (m1) { dst = 4 * __builtin_ctzll(m1) + 1; m1 &= m1 - 1; } \
            else if (m2) { dst = 4 * __builtin_ctzll(m2) + 2; m2 &= m2 - 1; } \
            else if (m3) { dst = 4 * __builtin_ctzll(m3) + 3; m3 &= m3 - 1; } \
        } while (0)

    // One LIF step. PC = ff slot for TC, PN = slot to fill for TC+2,
    // WC/WN = A/B parity for WT/seg3 buffers. LAST = final step.
    #define STEP(TC, PC, PN, WC, WN, LAST)                                    \
    {                                                                         \
        /* 1. membrane decay + spike decision */                              \
        const f32x4 vdec = vm + 0.1f * (cur - vm);                            \
        const f32x4 idec = cur * 0.8f;                                        \
        const bool z0 = vdec.x > 1.0f, z1 = vdec.y > 1.0f,                    \
                   z2 = vdec.z > 1.0f, z3 = vdec.w > 1.0f;                    \
        unsigned long long m0 = __ballot(z0), m1 = __ballot(z1),              \
                           m2 = __ballot(z2), m3 = __ballot(z3);              \
        vm.x = z0 ? 0.0f : vdec.x;  vm.y = z1 ? 0.0f : vdec.y;                \
        vm.z = z2 ? 0.0f : vdec.z;  vm.w = z3 ? 0.0f : vdec.w;                \
        n0 += z0; n1 += z1; n2 += z2; n3 += z3;                               \
        /* 2. consume prefetched ff + rec */                                  \
        f32x4 ff;                                                             \
        if constexpr (USEP2) ff = PC##a; else ff = PC##a + PC##b;             \
        if (HAS3(TC)) ff = ff + q##WC;                                        \
        f32x4 rec = rext##WC;                                                 \
        if (cnt##WC > 0) rec += w##WC##0;                                     \
        if (cnt##WC > 1) rec += w##WC##1;                                     \
        if (cnt##WC > 2) rec += w##WC##2;                                     \
        if (cnt##WC > 3) rec += w##WC##3;                                     \
        cur = (idec + ff) + rec;                                              \
        /* 3. issue ff rows for TC+2 (symbol-only addresses) */               \
        if ((TC) + 2 < T_STEPS) {                                             \
            const int f0_ = (((TC) + 2) * MF) >> 7;                           \
            if constexpr (USEP2) {                                            \
                PN##a = P2_4[((((TC) + 2) * 16 + sym[f0_]) * 16               \
                              + sym[f0_ + 1]) * 64 + lane];                   \
            } else {                                                          \
                PN##a = P4[((((TC) + 2) * 3 + 0) * 16 + sym[f0_    ]) * 64 + lane]; \
                PN##b = P4[((((TC) + 2) * 3 + 1) * 16 + sym[f0_ + 1]) * 64 + lane]; \
            }                                                                 \
        }                                                                     \
        /* 3b. seg3 row for TC+1 (8/32 steps) */                              \
        if ((TC) + 1 < T_STEPS && HAS3((TC) + 1)) {                           \
            const int f0q = (((TC) + 1) * MF) >> 7;                           \
            q##WN = P4[((((TC) + 1) * 3 + 2) * 16 + sym[f0q + 2]) * 64 + lane]; \
        }                                                                     \
        /* 4. peel + issue EXACTLY c WT rows for TC+1 */                      \
        if (!(LAST)) {                                                        \
            const int c_ = __popcll(m0) + __popcll(m1)                        \
                         + __popcll(m2) + __popcll(m3);                       \
            cnt##WN = c_;                                                     \
            rext##WN = zero4;                                                 \
            if (c_ > 0) {                                                     \
                int u_ = 256;                                                 \
                PEEL(u_); w##WN##0 = WT4[u_ * 64 + lane];                     \
                if (c_ > 1) {                                                 \
                    PEEL(u_); w##WN##1 = WT4[u_ * 64 + lane];                 \
                    if (c_ > 2) {                                             \
                        PEEL(u_); w##WN##2 = WT4[u_ * 64 + lane];             \
                        if (c_ > 3) {                                         \
                            PEEL(u_); w##WN##3 = WT4[u_ * 64 + lane];         \
                            if (c_ > 4) {    /* rare burst: synchronous */    \
                                while (m0) { const int l = __builtin_ctzll(m0); m0 &= m0 - 1; \
                                             rext##WN += WT4[(4 * l + 0) * 64 + lane]; } \
                                while (m1) { const int l = __builtin_ctzll(m1); m1 &= m1 - 1; \
                                             rext##WN += WT4[(4 * l + 1) * 64 + lane]; } \
                                while (m2) { const int l = __builtin_ctzll(m2); m2 &= m2 - 1; \
                                             rext##WN += WT4[(4 * l + 2) * 64 + lane]; } \
                                while (m3) { const int l = __builtin_ctzll(m3); m3 &= m3 - 1; \
                                             rext##WN += WT4[(4 * l + 3) * 64 + lane]; } \
                            }                                                 \
                        }                                                     \
                    }                                                         \
                }                                                             \
            }                                                                 \
        }                                                                     \
        __builtin_amdgcn_sched_barrier(0);                                    \
    }

    STEP( 0, p0, p2, A, B, 0)  STEP( 1, p1, p0, B, A, 0)  STEP( 2, p2, p1, A, B, 0)
    STEP( 3, p0, p2, B, A, 0)  STEP( 4, p1, p0, A, B, 0)  STEP( 5, p2, p1, B, A, 0)
    STEP( 6, p0, p2, A, B, 0)  STEP( 7, p1, p0, B, A, 0)  STEP( 8, p2, p1, A, B, 0)
    STEP( 9, p0, p2, B, A, 0)  STEP(10, p1, p0, A, B, 0)  STEP(11, p2, p1, B, A, 0)
    STEP(12, p0, p2, A, B, 0)  STEP(13, p1, p0, B, A, 0)  STEP(14, p2, p1, A, B, 0)
    STEP(15, p0, p2, B, A, 0)  STEP(16, p1, p0, A, B, 0)  STEP(17, p2, p1, B, A, 0)
    STEP(18, p0, p2, A, B, 0)  STEP(19, p1, p0, B, A, 0)  STEP(20, p2, p1, A, B, 0)
    STEP(21, p0, p2, B, A, 0)  STEP(22, p1, p0, A, B, 0)  STEP(23, p2, p1, B, A, 0)
    STEP(24, p0, p2, A, B, 0)  STEP(25, p1, p0, B, A, 0)  STEP(26, p2, p1, A, B, 0)
    STEP(27, p0, p2, B, A, 0)  STEP(28, p1, p0, A, B, 0)  STEP(29, p2, p1, B, A, 0)
    STEP(30, p0, p2, A, B, 0)  STEP(31, p1, p0, B, A, 1)

    #undef STEP
    #undef PEEL

    // --- publish per-h spike counts & block spike total ---
    cnt_lds[wv][4 * lane + 0] = (float)n0;
    cnt_lds[wv][4 * lane + 1] = (float)n1;
    cnt_lds[wv][4 * lane + 2] = (float)n2;
    cnt_lds[wv][4 * lane + 3] = (float)n3;

    int myspk = n0 + n1 + n2 + n3;
    #pragma unroll
    for (int off = 32; off > 0; off >>= 1)
        myspk += __shfl_down(myspk, off, 64);
    if (lane == 0) red[wv] = myspk;

    __syncthreads();
    if (tid == 0) atomicAdd(counter, red[0] + red[1] + red[2] + red[3]);

    // --- epilogue: z_sum[b,o] = 32*b_out[o] + sum_h cnt[h]*W_out[o,h] ---
    {
        const int o = lane & 15;
        const int q = lane >> 4;
        const float* __restrict__ wo = W_out + o * 256 + q * 64;
        const float* __restrict__ cl = cnt_lds[wv] + q * 64;
        float acc = 0.0f;
        #pragma unroll 8
        for (int h = 0; h < 64; ++h)
            acc += cl[h] * wo[h];
        acc += __shfl_down(acc, 16, 64);
        acc += __shfl_down(acc, 32, 64);
        if (q == 0)
            out[b * ODIM + o] = 32.0f * b_out[o] + acc;
    }
}

// ---------------------------------------------------------------------------
// K3: spikerate = count / 2^25 (exact in fp32 since count < 2^24)
// ---------------------------------------------------------------------------
__global__ void k_fin(const int* __restrict__ counter, float* __restrict__ out)
{
    out[BDIM * ODIM] = (float)(*counter) * (1.0f / 33554432.0f);
}

// ---------------------------------------------------------------------------
extern "C" void kernel_launch(void* const* d_in, const int* in_sizes, int n_in,
                              void* d_out, int out_size, void* d_ws, size_t ws_size,
                              hipStream_t stream)
{
    const int*   x     = (const int*)  d_in[0];
    const float* emb   = (const float*)d_in[1];
    const float* W_in  = (const float*)d_in[2];
    const float* W_rec = (const float*)d_in[3];
    const float* W_out = (const float*)d_in[4];
    const float* b_out = (const float*)d_in[5];
    float* out = (float*)d_out;

    char* ws = (char*)d_ws;
    float* P       = (float*)ws;
    float* WT      = (float*)(ws + WT_OFF);
    int*   counter = (int*)  (ws + CNT_OFF);
    float* P2      = (float*)(ws + P2_OFF);

    const bool useP2 = (ws_size >= (size_t)WS_NEED);

    k_prep<<<384 + 257, 256, 0, stream>>>(emb, W_in, W_rec, P, WT, counter);
    if (useP2) {
        k_comb<<<32 * 16, 256, 0, stream>>>(P, P2);
        k_main<true><<<BDIM / 4, 256, 0, stream>>>(x, P, P2, WT, W_out, b_out,
                                                   out, counter);
    } else {
        k_main<false><<<BDIM / 4, 256, 0, stream>>>(x, P, P2, WT, W_out, b_out,
                                                    out, counter);
    }
    k_fin<<<1, 1, 0, stream>>>(counter, out);
}